// Round 1
// baseline (3251.295 us; speedup 1.0000x reference)
//
#include <hip/hip_runtime.h>
#include <math.h>

#define TT 6
#define FC 24
#define KN 35
#define HW 65536
#define NPIX (TT*HW)   // 393216
#define CPB 16         // columns per block in col-FFT

__device__ inline float2 cmulf(float2 a, float2 b){
    return make_float2(a.x*b.x - a.y*b.y, a.x*b.y + a.y*b.x);
}

// ---------------- reduction: sum|X|^2 and sum(mask) ----------------
__global__ void reduce_kernel(const float* xr, const float* xi, const float* mask, float* sums){
    __shared__ float s1[256], s2[256];
    int tid = threadIdx.x;
    int gid = blockIdx.x*256 + tid;
    float a = 0.f, b = 0.f;
    for (int i = gid; i < NPIX; i += gridDim.x*256) a += xr[i]*xr[i] + xi[i]*xi[i];
    for (int i = gid; i < TT*256; i += gridDim.x*256) b += mask[i];
    s1[tid]=a; s2[tid]=b; __syncthreads();
    for (int off=128; off>0; off>>=1){
        if (tid<off){ s1[tid]+=s1[tid+off]; s2[tid]+=s2[tid+off]; }
        __syncthreads();
    }
    if (tid==0){ atomicAdd(&sums[0], s1[0]); atomicAdd(&sums[1], s2[0]); }
}

// ---------------- normalize: Xks = (xr + i xi)/norm ----------------
__global__ void normalize_kernel(const float* xr, const float* xi, const float* sums, float2* Xks){
    int i = blockIdx.x*256 + threadIdx.x;
    float inv = rsqrtf(sums[0]/sums[1]);
    Xks[i] = make_float2(xr[i]*inv, xi[i]*inv);
}

// ---------------- FFT row pass (along W), centered, 2 lines/block ----------------
// out[k] = (-1)^k * scale * FFT_dir( (-1)^n * in[n] )[k]
__global__ void fft_row_kernel(const float2* __restrict__ in, float2* __restrict__ out,
                               float dir, float scale){
    __shared__ float2 lds[2][256];
    __shared__ float2 tw[128];
    int tid = threadIdx.x;
    int line = tid >> 7;      // 0..1
    int j = tid & 127;
    if (tid < 128){
        float s, c;
        sincosf(dir * 6.283185307179586f * (float)tid / 256.0f, &s, &c);
        tw[tid] = make_float2(c, s);
    }
    long gline = (long)blockIdx.x*2 + line;
    const float2* src = in + gline*256;
    {
        float sg = (j & 1) ? -1.f : 1.f;   // parity of j and j+128 identical
        float2 a = src[j];
        float2 b = src[j+128];
        lds[line][j]     = make_float2(a.x*sg, a.y*sg);
        lds[line][j+128] = make_float2(b.x*sg, b.y*sg);
    }
    __syncthreads();
    for (int s = 0; s < 8; s++){
        int half = 128 >> s;
        int pos = j & (half-1);
        int grp = j >> (7-s);
        int i0 = (grp << (8-s)) + pos;
        int i1 = i0 + half;
        float2 u = lds[line][i0], v = lds[line][i1];
        float2 w = tw[pos << s];
        lds[line][i0] = make_float2(u.x+v.x, u.y+v.y);
        float2 d = make_float2(u.x-v.x, u.y-v.y);
        lds[line][i1] = cmulf(d, w);
        __syncthreads();
    }
    float2* dst = out + gline*256;
    {
        int k = j;
        float sg = (k & 1) ? -scale : scale;
        float2 v = lds[line][__brev((unsigned)k) >> 24];
        dst[k] = make_float2(v.x*sg, v.y*sg);
        k = j + 128;
        sg = (k & 1) ? -scale : scale;
        v = lds[line][__brev((unsigned)k) >> 24];
        dst[k] = make_float2(v.x*sg, v.y*sg);
    }
}

// ---------------- FFT col pass (along H), centered, 16 cols/block ----------------
__global__ void fft_col_kernel(const float2* __restrict__ in, float2* __restrict__ out,
                               float dir, float scale, const float* k0 /*nullable*/){
    __shared__ float2 lds[256][CPB+1];
    __shared__ float2 tw[128];
    int tid = threadIdx.x;
    if (tid < 128){
        float s, c;
        sincosf(dir * 6.283185307179586f * (float)tid / 256.0f, &s, &c);
        tw[tid] = make_float2(c, s);
    }
    int t  = blockIdx.x / (256/CPB);
    int w0 = (blockIdx.x % (256/CPB)) * CPB;
    const float2* src = in + (long)t*HW;
    float2* dst = out + (long)t*HW;
    int c  = tid & (CPB-1);
    int h0 = tid >> 4;   // 0..15
    for (int i = 0; i < 16; i++){
        int h = h0 + 16*i;
        float2 v = src[h*256 + w0 + c];
        float sg = (h & 1) ? -1.f : 1.f;
        lds[h][c] = make_float2(v.x*sg, v.y*sg);
    }
    __syncthreads();
    int jb = tid >> 4;   // 0..15
    for (int s = 0; s < 8; s++){
        int half = 128 >> s;
        for (int i = 0; i < 8; i++){
            int j = jb + 16*i;      // 0..127
            int pos = j & (half-1);
            int grp = j >> (7-s);
            int i0 = (grp << (8-s)) + pos;
            int i1 = i0 + half;
            float2 u = lds[i0][c], v = lds[i1][c];
            float2 w = tw[pos << s];
            lds[i0][c] = make_float2(u.x+v.x, u.y+v.y);
            float2 d = make_float2(u.x-v.x, u.y-v.y);
            lds[i1][c] = cmulf(d, w);
        }
        __syncthreads();
    }
    float mul = scale;
    if (k0) mul *= *k0;
    for (int i = 0; i < 16; i++){
        int k = h0 + 16*i;
        float2 v = lds[__brev((unsigned)k) >> 24][c];
        float sg = (k & 1) ? -mul : mul;
        dst[k*256 + w0 + c] = make_float2(v.x*sg, v.y*sg);
    }
}

// ---------------- forward complex conv 1->24, 11x11, SAME ----------------
__global__ __launch_bounds__(256) void conv_fwd_kernel(const float2* __restrict__ Ximg,
                                                       const float* __restrict__ Dr,
                                                       const float* __restrict__ Di,
                                                       float2* __restrict__ DX){
    __shared__ float2 xt[26][27];
    int t  = blockIdx.z;
    int h0 = blockIdx.y*16, w0 = blockIdx.x*16;
    int tx = threadIdx.x & 15, ty = threadIdx.x >> 4;
    const float2* src = Ximg + (long)t*HW;
    for (int i = threadIdx.x; i < 26*26; i += 256){
        int yy = i / 26, xx = i % 26;
        int gh = h0 + yy - 5, gw = w0 + xx - 5;
        float2 v = make_float2(0.f, 0.f);
        if (gh >= 0 && gh < 256 && gw >= 0 && gw < 256) v = src[gh*256 + gw];
        xt[yy][xx] = v;
    }
    __syncthreads();
    float2 acc[24];
    #pragma unroll
    for (int f = 0; f < 24; f++) acc[f] = make_float2(0.f, 0.f);
    for (int ky = 0; ky < 11; ky++){
        #pragma unroll
        for (int kx = 0; kx < 11; kx++){
            float2 xv = xt[ty+ky][tx+kx];
            int widx = ky*11 + kx;
            #pragma unroll
            for (int f = 0; f < 24; f++){
                float wr = Dr[f*121 + widx];   // wave-uniform -> s_load
                float wi = Di[f*121 + widx];
                acc[f].x = fmaf(xv.x, wr, fmaf(-xv.y, wi, acc[f].x));
                acc[f].y = fmaf(xv.x, wi, fmaf( xv.y, wr, acc[f].y));
            }
        }
    }
    int h = h0 + ty, w = w0 + tx;
    #pragma unroll
    for (int f = 0; f < 24; f++)
        DX[((long)(t*24+f))*HW + h*256 + w] = acc[f];
}

// ---------------- spline activation + V = DX*act (fused over T) ----------------
__global__ void act_mul_kernel(float2* __restrict__ DX, const float* __restrict__ knots){
    int id = blockIdx.x*256 + threadIdx.x;   // over 24*HW
    int f   = id >> 16;
    int pix = id & 65535;
    float2 v[6];
    float s = 0.f;
    #pragma unroll
    for (int t = 0; t < 6; t++){
        v[t] = DX[((long)(t*24+f))*HW + pix];
        s += v[t].x*v[t].x + v[t].y*v[t].y;
    }
    float act_in = sqrtf(s) * (1.0f/6.0f);
    float pos = fminf(fmaxf(act_in * 34.0f, 0.0f), 34.0f);
    int i0 = (int)pos; if (i0 > 33) i0 = 33;
    float frac = pos - (float)i0;
    float k0v = knots[i0*24 + f];
    float k1v = knots[(i0+1)*24 + f];
    float a = k0v*(1.0f - frac) + k1v*frac;
    #pragma unroll
    for (int t = 0; t < 6; t++)
        DX[((long)(t*24+f))*HW + pix] = make_float2(v[t].x*a, v[t].y*a);
}

// ---------------- adjoint complex conv 24->1 ----------------
__global__ __launch_bounds__(256) void conv_adj_kernel(const float2* __restrict__ DX,
                                                       const float* __restrict__ Dr,
                                                       const float* __restrict__ Di,
                                                       float2* __restrict__ rg){
    __shared__ float2 vt[26][27];
    int t  = blockIdx.z;
    int h0 = blockIdx.y*16, w0 = blockIdx.x*16;
    int tx = threadIdx.x & 15, ty = threadIdx.x >> 4;
    float2 acc = make_float2(0.f, 0.f);
    for (int f = 0; f < 24; f++){
        const float2* src = DX + ((long)(t*24+f))*HW;
        __syncthreads();
        for (int i = threadIdx.x; i < 26*26; i += 256){
            int yy = i / 26, xx = i % 26;
            int gh = h0 + yy - 5, gw = w0 + xx - 5;
            float2 v = make_float2(0.f, 0.f);
            if (gh >= 0 && gh < 256 && gw >= 0 && gw < 256) v = src[gh*256 + gw];
            vt[yy][xx] = v;
        }
        __syncthreads();
        for (int ky = 0; ky < 11; ky++){
            #pragma unroll
            for (int kx = 0; kx < 11; kx++){
                float2 vv = vt[ty+ky][tx+kx];
                float wr = Dr[f*121 + (10-ky)*11 + (10-kx)];
                float wi = Di[f*121 + (10-ky)*11 + (10-kx)];
                acc.x = fmaf(vv.x, wr, fmaf( vv.y, wi, acc.x));
                acc.y = fmaf(vv.y, wr, fmaf(-vv.x, wi, acc.y));
            }
        }
    }
    rg[(long)t*HW + (h0+ty)*256 + (w0+tx)] = acc;
}

// ---------------- k-space mask + subtract ----------------
__global__ void masksub_kernel(float2* __restrict__ tmp, const float* __restrict__ mask,
                               const float2* __restrict__ Xks){
    int i = blockIdx.x*256 + threadIdx.x;
    int t = i >> 16;
    int w = i & 255;
    float mv = mask[t*256 + w];
    float2 v = tmp[i], x = Xks[i];
    tmp[i] = make_float2(v.x*mv - x.x, v.y*mv - x.y);
}

// ---------------- momentum update ----------------
__global__ void update_kernel(float2* __restrict__ Ximg, float2* __restrict__ m,
                              const float2* __restrict__ dg, const float2* __restrict__ rg,
                              const float* __restrict__ alphas, const float* __restrict__ moms, int l){
    int i = blockIdx.x*256 + threadIdx.x;
    float a  = alphas[l];
    float mu = moms[l];
    float2 g  = make_float2(fmaf(a, dg[i].x, rg[i].x), fmaf(a, dg[i].y, rg[i].y));
    float2 mm = make_float2(fmaf(mu, m[i].x, g.x),     fmaf(mu, m[i].y, g.y));
    m[i] = mm;
    float2 xi = Ximg[i];
    Ximg[i] = make_float2(xi.x - mm.x, xi.y - mm.y);
}

// ---------------- output: stack(real, imag)*norm ----------------
__global__ void output_kernel(const float2* __restrict__ Ximg, const float* __restrict__ sums,
                              float* __restrict__ out){
    int i = blockIdx.x*256 + threadIdx.x;
    float norm = sqrtf(sums[0]/sums[1]);
    float2 v = Ximg[i];
    out[2*i]   = v.x * norm;
    out[2*i+1] = v.y * norm;
}

extern "C" void kernel_launch(void* const* d_in, const int* in_sizes, int n_in,
                              void* d_out, int out_size, void* d_ws, size_t ws_size,
                              hipStream_t stream){
    const float* Xr    = (const float*)d_in[0];
    const float* Xi    = (const float*)d_in[1];
    const float* mask  = (const float*)d_in[2];
    const float* kr    = (const float*)d_in[3];
    const float* ki    = (const float*)d_in[4];
    const float* knots = (const float*)d_in[5];
    const float* alph  = (const float*)d_in[6];
    const float* moms  = (const float*)d_in[7];
    const float* k0    = (const float*)d_in[8];

    float*  ws   = (float*)d_ws;
    float*  sums = ws;                       // 2 floats used (pad to 16)
    float2* Xks  = (float2*)(ws + 16);
    float2* Ximg = Xks  + NPIX;
    float2* mbuf = Ximg + NPIX;
    float2* tmp  = mbuf + NPIX;
    float2* rg   = tmp  + NPIX;
    float2* DX   = rg   + NPIX;              // 6*24*HW float2 = 75.5 MB

    const float OS = 1.0f/16.0f;             // ortho scale per 1D pass

    hipMemsetAsync(sums, 0, 2*sizeof(float), stream);
    hipMemsetAsync(mbuf, 0, (size_t)NPIX*sizeof(float2), stream);

    reduce_kernel<<<384, 256, 0, stream>>>(Xr, Xi, mask, sums);
    normalize_kernel<<<NPIX/256, 256, 0, stream>>>(Xr, Xi, sums, Xks);

    // X_img = k2i(Xks) * k0   (k2i = centered inverse FFT, dir=+1)
    fft_row_kernel<<<TT*128, 256, 0, stream>>>(Xks, tmp, +1.0f, OS);
    fft_col_kernel<<<TT*(256/CPB), 256, 0, stream>>>(tmp, Ximg, +1.0f, OS, k0);

    for (int l = 0; l < 8; l++){
        const float* Dr = kr + (long)l*FC*121;
        const float* Di = ki + (long)l*FC*121;
        conv_fwd_kernel<<<dim3(16,16,TT), 256, 0, stream>>>(Ximg, Dr, Di, DX);
        act_mul_kernel<<<(FC*HW)/256, 256, 0, stream>>>(DX, knots + (long)l*KN*FC);
        conv_adj_kernel<<<dim3(16,16,TT), 256, 0, stream>>>(DX, Dr, Di, rg);
        // data consistency: tmp = i2k(Ximg); tmp = tmp*mask - Xks; tmp = k2i(tmp)
        fft_row_kernel<<<TT*128, 256, 0, stream>>>(Ximg, tmp, -1.0f, OS);
        fft_col_kernel<<<TT*(256/CPB), 256, 0, stream>>>(tmp, tmp, -1.0f, OS, nullptr);
        masksub_kernel<<<NPIX/256, 256, 0, stream>>>(tmp, mask, Xks);
        fft_row_kernel<<<TT*128, 256, 0, stream>>>(tmp, tmp, +1.0f, OS);
        fft_col_kernel<<<TT*(256/CPB), 256, 0, stream>>>(tmp, tmp, +1.0f, OS, nullptr);
        update_kernel<<<NPIX/256, 256, 0, stream>>>(Ximg, mbuf, tmp, rg, alph, moms, l);
    }

    output_kernel<<<NPIX/256, 256, 0, stream>>>(Ximg, sums, (float*)d_out);
}

// Round 2
// 3021.621 us; speedup vs baseline: 1.0760x; 1.0760x over previous
//
#include <hip/hip_runtime.h>
#include <math.h>

#define TT 6
#define FC 24
#define KN 35
#define HW 65536
#define NPIX (TT*HW)   // 393216
#define CPB 16         // columns per block in col-FFT

__device__ inline float2 cmulf(float2 a, float2 b){
    return make_float2(a.x*b.x - a.y*b.y, a.x*b.y + a.y*b.x);
}

// ---------------- reduction: sum|X|^2 and sum(mask) ----------------
__global__ void reduce_kernel(const float* xr, const float* xi, const float* mask, float* sums){
    __shared__ float s1[256], s2[256];
    int tid = threadIdx.x;
    int gid = blockIdx.x*256 + tid;
    float a = 0.f, b = 0.f;
    for (int i = gid; i < NPIX; i += gridDim.x*256) a += xr[i]*xr[i] + xi[i]*xi[i];
    for (int i = gid; i < TT*256; i += gridDim.x*256) b += mask[i];
    s1[tid]=a; s2[tid]=b; __syncthreads();
    for (int off=128; off>0; off>>=1){
        if (tid<off){ s1[tid]+=s1[tid+off]; s2[tid]+=s2[tid+off]; }
        __syncthreads();
    }
    if (tid==0){ atomicAdd(&sums[0], s1[0]); atomicAdd(&sums[1], s2[0]); }
}

// ---------------- normalize: Xks = (xr + i xi)/norm ----------------
__global__ void normalize_kernel(const float* xr, const float* xi, const float* sums, float2* Xks){
    int i = blockIdx.x*256 + threadIdx.x;
    float inv = rsqrtf(sums[0]/sums[1]);
    Xks[i] = make_float2(xr[i]*inv, xi[i]*inv);
}

// ---------------- weight repack: fwd [l][tap][f][ri], adj [l][f][tap-flipped][ri] ----------------
__global__ void repack_kernel(const float* kr, const float* ki, float* Wf, float* Wa){
    int i = blockIdx.x*256 + threadIdx.x;
    if (i >= 8*121*24) return;
    int f   = i % 24;
    int tap = (i/24) % 121;
    int l   = i/(24*121);
    long src = (long)(l*24+f)*121;
    Wf[(((long)l*121+tap)*24+f)*2+0] = kr[src+tap];
    Wf[(((long)l*121+tap)*24+f)*2+1] = ki[src+tap];
    Wa[(((long)l*24+f)*121+tap)*2+0] = kr[src+120-tap];   // spatial flip baked in
    Wa[(((long)l*24+f)*121+tap)*2+1] = ki[src+120-tap];
}

// ---------------- FFT row pass (along W), centered, 2 lines/block ----------------
__global__ void fft_row_kernel(const float2* __restrict__ in, float2* __restrict__ out,
                               float dir, float scale){
    __shared__ float2 lds[2][256];
    __shared__ float2 tw[128];
    int tid = threadIdx.x;
    int line = tid >> 7;
    int j = tid & 127;
    if (tid < 128){
        float s, c;
        sincosf(dir * 6.283185307179586f * (float)tid / 256.0f, &s, &c);
        tw[tid] = make_float2(c, s);
    }
    long gline = (long)blockIdx.x*2 + line;
    const float2* src = in + gline*256;
    {
        float sg = (j & 1) ? -1.f : 1.f;
        float2 a = src[j];
        float2 b = src[j+128];
        lds[line][j]     = make_float2(a.x*sg, a.y*sg);
        lds[line][j+128] = make_float2(b.x*sg, b.y*sg);
    }
    __syncthreads();
    for (int s = 0; s < 8; s++){
        int half = 128 >> s;
        int pos = j & (half-1);
        int grp = j >> (7-s);
        int i0 = (grp << (8-s)) + pos;
        int i1 = i0 + half;
        float2 u = lds[line][i0], v = lds[line][i1];
        float2 w = tw[pos << s];
        lds[line][i0] = make_float2(u.x+v.x, u.y+v.y);
        float2 d = make_float2(u.x-v.x, u.y-v.y);
        lds[line][i1] = cmulf(d, w);
        __syncthreads();
    }
    float2* dst = out + gline*256;
    {
        int k = j;
        float sg = (k & 1) ? -scale : scale;
        float2 v = lds[line][__brev((unsigned)k) >> 24];
        dst[k] = make_float2(v.x*sg, v.y*sg);
        k = j + 128;
        sg = (k & 1) ? -scale : scale;
        v = lds[line][__brev((unsigned)k) >> 24];
        dst[k] = make_float2(v.x*sg, v.y*sg);
    }
}

// ---------------- FFT col pass (along H), centered, 16 cols/block ----------------
__global__ void fft_col_kernel(const float2* __restrict__ in, float2* __restrict__ out,
                               float dir, float scale, const float* k0 /*nullable*/){
    __shared__ float2 lds[256][CPB+1];
    __shared__ float2 tw[128];
    int tid = threadIdx.x;
    if (tid < 128){
        float s, c;
        sincosf(dir * 6.283185307179586f * (float)tid / 256.0f, &s, &c);
        tw[tid] = make_float2(c, s);
    }
    int t  = blockIdx.x / (256/CPB);
    int w0 = (blockIdx.x % (256/CPB)) * CPB;
    const float2* src = in + (long)t*HW;
    float2* dst = out + (long)t*HW;
    int c  = tid & (CPB-1);
    int h0 = tid >> 4;
    for (int i = 0; i < 16; i++){
        int h = h0 + 16*i;
        float2 v = src[h*256 + w0 + c];
        float sg = (h & 1) ? -1.f : 1.f;
        lds[h][c] = make_float2(v.x*sg, v.y*sg);
    }
    __syncthreads();
    int jb = tid >> 4;
    for (int s = 0; s < 8; s++){
        int half = 128 >> s;
        for (int i = 0; i < 8; i++){
            int j = jb + 16*i;
            int pos = j & (half-1);
            int grp = j >> (7-s);
            int i0 = (grp << (8-s)) + pos;
            int i1 = i0 + half;
            float2 u = lds[i0][c], v = lds[i1][c];
            float2 w = tw[pos << s];
            lds[i0][c] = make_float2(u.x+v.x, u.y+v.y);
            float2 d = make_float2(u.x-v.x, u.y-v.y);
            lds[i1][c] = cmulf(d, w);
        }
        __syncthreads();
    }
    float mul = scale;
    if (k0) mul *= *k0;
    for (int i = 0; i < 16; i++){
        int k = h0 + 16*i;
        float2 v = lds[__brev((unsigned)k) >> 24][c];
        float sg = (k & 1) ? -mul : mul;
        dst[k*256 + w0 + c] = make_float2(v.x*sg, v.y*sg);
    }
}

// ---------------- forward complex conv 1->24, 11x11, SAME ----------------
// weights: wt[tap*48 + 2f], wt[tap*48 + 2f + 1]   (contiguous per tap -> s_load_dwordx16)
__global__ __launch_bounds__(256) void conv_fwd_kernel(const float2* __restrict__ Ximg,
                                                       const float* __restrict__ wt,
                                                       float2* __restrict__ DX){
    __shared__ float2 xt[26][27];
    int t  = blockIdx.z;
    int h0 = blockIdx.y*16, w0 = blockIdx.x*16;
    int tx = threadIdx.x & 15, ty = threadIdx.x >> 4;
    const float2* src = Ximg + (long)t*HW;
    for (int i = threadIdx.x; i < 26*26; i += 256){
        int yy = i / 26, xx = i % 26;
        int gh = h0 + yy - 5, gw = w0 + xx - 5;
        float2 v = make_float2(0.f, 0.f);
        if (gh >= 0 && gh < 256 && gw >= 0 && gw < 256) v = src[gh*256 + gw];
        xt[yy][xx] = v;
    }
    __syncthreads();
    float2 acc[24];
    #pragma unroll
    for (int f = 0; f < 24; f++) acc[f] = make_float2(0.f, 0.f);
    for (int ky = 0; ky < 11; ky++){
        #pragma unroll
        for (int kx = 0; kx < 11; kx++){
            float2 xv = xt[ty+ky][tx+kx];
            const float* wp = wt + (ky*11 + kx)*48;
            #pragma unroll
            for (int f = 0; f < 24; f++){
                float wr = wp[2*f];
                float wi = wp[2*f+1];
                acc[f].x = fmaf(xv.x, wr, fmaf(-xv.y, wi, acc[f].x));
                acc[f].y = fmaf(xv.x, wi, fmaf( xv.y, wr, acc[f].y));
            }
        }
    }
    int h = h0 + ty, w = w0 + tx;
    #pragma unroll
    for (int f = 0; f < 24; f++)
        DX[((long)(t*24+f))*HW + h*256 + w] = acc[f];
}

// ---------------- spline activation + V = DX*act (fused over T) ----------------
__global__ void act_mul_kernel(float2* __restrict__ DX, const float* __restrict__ knots){
    int id = blockIdx.x*256 + threadIdx.x;   // over 24*HW
    int f   = id >> 16;
    int pix = id & 65535;
    float2 v[6];
    float s = 0.f;
    #pragma unroll
    for (int t = 0; t < 6; t++){
        v[t] = DX[((long)(t*24+f))*HW + pix];
        s += v[t].x*v[t].x + v[t].y*v[t].y;
    }
    float act_in = sqrtf(s) * (1.0f/6.0f);
    float pos = fminf(fmaxf(act_in * 34.0f, 0.0f), 34.0f);
    int i0 = (int)pos; if (i0 > 33) i0 = 33;
    float frac = pos - (float)i0;
    float k0v = knots[i0*24 + f];
    float k1v = knots[(i0+1)*24 + f];
    float a = k0v*(1.0f - frac) + k1v*frac;
    #pragma unroll
    for (int t = 0; t < 6; t++)
        DX[((long)(t*24+f))*HW + pix] = make_float2(v[t].x*a, v[t].y*a);
}

// ---------------- adjoint complex conv 24->1, 16x64 tile, 4 rows/thread ----------------
// z = part*6 + t ; part handles f in [part*12, part*12+12), writes rg + part*NPIX
// weights: wa[f*242 + tap*2 + {0,1}] with spatial flip pre-applied
__global__ __launch_bounds__(256) void conv_adj_kernel(const float2* __restrict__ DX,
                                                       const float* __restrict__ wa,
                                                       float2* __restrict__ rg){
    __shared__ float2 vt[74][26];
    int z = blockIdx.z;
    int t = z % 6, part = z / 6;
    int h0 = blockIdx.y*64, w0 = blockIdx.x*16;
    int tx = threadIdx.x & 15;
    int r0 = (threadIdx.x >> 4) * 4;   // 0..60
    float2 acc[4];
    #pragma unroll
    for (int r = 0; r < 4; r++) acc[r] = make_float2(0.f, 0.f);
    int f0 = part*12;
    #pragma unroll 1
    for (int f = f0; f < f0+12; f++){
        const float2* src = DX + ((long)(t*24+f))*HW;
        __syncthreads();
        for (int i = threadIdx.x; i < 74*26; i += 256){
            int yy = i / 26, xx = i % 26;
            int gh = h0 + yy - 5, gw = w0 + xx - 5;
            float2 v = make_float2(0.f, 0.f);
            if (gh >= 0 && gh < 256 && gw >= 0 && gw < 256) v = src[gh*256 + gw];
            vt[yy][xx] = v;
        }
        __syncthreads();
        const float* wf = wa + f*242;
        #pragma unroll
        for (int sr = 0; sr < 14; sr++){
            float2 v[11];
            #pragma unroll
            for (int kx = 0; kx < 11; kx++) v[kx] = vt[r0+sr][tx+kx];
            #pragma unroll
            for (int rr = 0; rr < 4; rr++){
                int ky = sr - rr;
                if (ky < 0 || ky > 10) continue;   // resolved at compile time
                #pragma unroll
                for (int kx = 0; kx < 11; kx++){
                    float wr = wf[(ky*11+kx)*2+0];
                    float wi = wf[(ky*11+kx)*2+1];
                    acc[rr].x = fmaf(v[kx].x, wr, fmaf( v[kx].y, wi, acc[rr].x));
                    acc[rr].y = fmaf(v[kx].y, wr, fmaf(-v[kx].x, wi, acc[rr].y));
                }
            }
        }
    }
    float2* out = rg + (long)part*NPIX + (long)t*HW;
    #pragma unroll
    for (int rr = 0; rr < 4; rr++)
        out[(h0 + r0 + rr)*256 + (w0 + tx)] = acc[rr];
}

// ---------------- k-space mask + subtract ----------------
__global__ void masksub_kernel(float2* __restrict__ tmp, const float* __restrict__ mask,
                               const float2* __restrict__ Xks){
    int i = blockIdx.x*256 + threadIdx.x;
    int t = i >> 16;
    int w = i & 255;
    float mv = mask[t*256 + w];
    float2 v = tmp[i], x = Xks[i];
    tmp[i] = make_float2(v.x*mv - x.x, v.y*mv - x.y);
}

// ---------------- momentum update (rg = rg0 + rg1 partials) ----------------
__global__ void update_kernel(float2* __restrict__ Ximg, float2* __restrict__ m,
                              const float2* __restrict__ dg, const float2* __restrict__ rg,
                              const float* __restrict__ alphas, const float* __restrict__ moms, int l){
    int i = blockIdx.x*256 + threadIdx.x;
    float a  = alphas[l];
    float mu = moms[l];
    float2 r0 = rg[i], r1 = rg[i + NPIX];
    float2 g  = make_float2(fmaf(a, dg[i].x, r0.x + r1.x), fmaf(a, dg[i].y, r0.y + r1.y));
    float2 mm = make_float2(fmaf(mu, m[i].x, g.x),         fmaf(mu, m[i].y, g.y));
    m[i] = mm;
    float2 xi = Ximg[i];
    Ximg[i] = make_float2(xi.x - mm.x, xi.y - mm.y);
}

// ---------------- output: stack(real, imag)*norm ----------------
__global__ void output_kernel(const float2* __restrict__ Ximg, const float* __restrict__ sums,
                              float* __restrict__ out){
    int i = blockIdx.x*256 + threadIdx.x;
    float norm = sqrtf(sums[0]/sums[1]);
    float2 v = Ximg[i];
    out[2*i]   = v.x * norm;
    out[2*i+1] = v.y * norm;
}

extern "C" void kernel_launch(void* const* d_in, const int* in_sizes, int n_in,
                              void* d_out, int out_size, void* d_ws, size_t ws_size,
                              hipStream_t stream){
    const float* Xr    = (const float*)d_in[0];
    const float* Xi    = (const float*)d_in[1];
    const float* mask  = (const float*)d_in[2];
    const float* kr    = (const float*)d_in[3];
    const float* ki    = (const float*)d_in[4];
    const float* knots = (const float*)d_in[5];
    const float* alph  = (const float*)d_in[6];
    const float* moms  = (const float*)d_in[7];
    const float* k0    = (const float*)d_in[8];

    float*  ws   = (float*)d_ws;
    float*  sums = ws;                        // 2 floats used (pad to 16)
    float*  Wf   = ws + 16;                   // 8*121*48 = 46464 floats
    float*  Wa   = Wf + 8*121*48;             // 46464 floats
    float2* Xks  = (float2*)(Wa + 8*121*48);
    float2* Ximg = Xks  + NPIX;
    float2* mbuf = Ximg + NPIX;
    float2* tmp  = mbuf + NPIX;
    float2* rg   = tmp  + NPIX;               // 2*NPIX (two partials)
    float2* DX   = rg   + 2*NPIX;             // 6*24*HW float2 = 75.5 MB

    const float OS = 1.0f/16.0f;              // ortho scale per 1D pass

    hipMemsetAsync(sums, 0, 2*sizeof(float), stream);
    hipMemsetAsync(mbuf, 0, (size_t)NPIX*sizeof(float2), stream);

    repack_kernel<<<(8*121*24 + 255)/256, 256, 0, stream>>>(kr, ki, Wf, Wa);
    reduce_kernel<<<384, 256, 0, stream>>>(Xr, Xi, mask, sums);
    normalize_kernel<<<NPIX/256, 256, 0, stream>>>(Xr, Xi, sums, Xks);

    // X_img = k2i(Xks) * k0   (k2i = centered inverse FFT, dir=+1)
    fft_row_kernel<<<TT*128, 256, 0, stream>>>(Xks, tmp, +1.0f, OS);
    fft_col_kernel<<<TT*(256/CPB), 256, 0, stream>>>(tmp, Ximg, +1.0f, OS, k0);

    for (int l = 0; l < 8; l++){
        conv_fwd_kernel<<<dim3(16,16,TT), 256, 0, stream>>>(Ximg, Wf + (long)l*121*48, DX);
        act_mul_kernel<<<(FC*HW)/256, 256, 0, stream>>>(DX, knots + (long)l*KN*FC);
        conv_adj_kernel<<<dim3(16,4,2*TT), 256, 0, stream>>>(DX, Wa + (long)l*24*242, rg);
        // data consistency: tmp = i2k(Ximg); tmp = tmp*mask - Xks; tmp = k2i(tmp)
        fft_row_kernel<<<TT*128, 256, 0, stream>>>(Ximg, tmp, -1.0f, OS);
        fft_col_kernel<<<TT*(256/CPB), 256, 0, stream>>>(tmp, tmp, -1.0f, OS, nullptr);
        masksub_kernel<<<NPIX/256, 256, 0, stream>>>(tmp, mask, Xks);
        fft_row_kernel<<<TT*128, 256, 0, stream>>>(tmp, tmp, +1.0f, OS);
        fft_col_kernel<<<TT*(256/CPB), 256, 0, stream>>>(tmp, tmp, +1.0f, OS, nullptr);
        update_kernel<<<NPIX/256, 256, 0, stream>>>(Ximg, mbuf, tmp, rg, alph, moms, l);
    }

    output_kernel<<<NPIX/256, 256, 0, stream>>>(Ximg, sums, (float*)d_out);
}